// Round 12
// baseline (66.567 us; speedup 1.0000x reference)
//
#include <hip/hip_runtime.h>
#include <stdint.h>
#include <math.h>

#define B_SZ   2048
#define D_SZ   128
#define C_SZ   100000
#define S_SC   30.0f
#define C2LOG  43.2808512f                // 30*log2(e)
#define M2LOG  12.9837726f                // 9*log2(e)
#define A_QS   173.1234048f               // fp8 quant scale for f: C2LOG*4
#define B_QS   256.0f                     // fp8 quant scale for w
#define SCL_A  0x7D7D7D7Du                // e8m0 125 = 2^-2 (all 4 bytes)
#define SCL_B  0x77777777u                // e8m0 119 = 2^-8

// Barrier-free tiling: 256 thr = 4 INDEPENDENT waves, each owns 64 rows and
// an 8KB private LDS slice (A staged once, then 2x4KB B ping-pong).
// Per block: 256 rows x CPB cols. No s_barrier anywhere in the GEMM.
#define BM     256                        // rows per block (64 per wave)
#define BN     32                         // cols per B subtile (4KB)
#define NSUB   16
#define CPB    (BN*NSUB)                  // 512 cols per block
#define GRID_C ((C_SZ + CPB - 1)/CPB)     // 196
#define C_PAD  (GRID_C*CPB)               // 100352
// 352 pad cols (2^0 each) + zero-primed acc1 epilogue (+16 per (row,cb) slot
// x 196 slots = 3136) -> subtract exactly in merge.
#define POST_SUB 3488.0f
#define NSLOT  GRID_C                     // 196 partial slots per row

typedef float f32x4 __attribute__((ext_vector_type(4)));
typedef int   i32x4 __attribute__((ext_vector_type(4)));
typedef int   i32x8 __attribute__((ext_vector_type(8)));
typedef unsigned char u8;

__device__ __forceinline__ void gload_lds16(const void* g, void* l) {
  __builtin_amdgcn_global_load_lds(
      (const __attribute__((address_space(1))) void*)g,
      (__attribute__((address_space(3))) void*)l, 16, 0, 0);
}

// ------- row L2-normalize (x qscale) -> fp8 e4m3; rows >= valid_rows zeroed -------
__global__ void rownorm_fp8_kernel(const float* __restrict__ in,
                                   u8* __restrict__ out, int rows,
                                   int valid_rows, float scale) {
  int row  = (blockIdx.x * blockDim.x + threadIdx.x) >> 6;
  int lane = threadIdx.x & 63;
  if (row >= rows) return;
  if (row >= valid_rows) {
    ((unsigned short*)(out + (size_t)row * D_SZ))[lane] = 0;
    return;
  }
  float2 v = ((const float2*)(in + (size_t)row * D_SZ))[lane];
  float ss = v.x * v.x + v.y * v.y;
  #pragma unroll
  for (int m = 1; m < 64; m <<= 1) ss += __shfl_xor(ss, m, 64);
  float rn = scale / sqrtf(ss);
  int pk = __builtin_amdgcn_cvt_pk_fp8_f32(v.x * rn, v.y * rn, 0, false);
  ((unsigned short*)(out + (size_t)row * D_SZ))[lane] = (unsigned short)(pk & 0xFFFF);
}

// ------- fused: normalize+quantize f rows AND exact fp32 label cos -------
__global__ void prep_f_kernel(const float* __restrict__ f,
                              const int* __restrict__ labels,
                              const float* __restrict__ w,
                              u8* __restrict__ fn, float* __restrict__ cosy) {
  int row  = (blockIdx.x * blockDim.x + threadIdx.x) >> 6;
  int lane = threadIdx.x & 63;
  if (row >= B_SZ) return;
  float2 fv = ((const float2*)(f + (size_t)row * D_SZ))[lane];
  float ff = fv.x * fv.x + fv.y * fv.y;
  #pragma unroll
  for (int m = 1; m < 64; m <<= 1) ff += __shfl_xor(ff, m, 64);
  float rn = A_QS / sqrtf(ff);
  int pk = __builtin_amdgcn_cvt_pk_fp8_f32(fv.x * rn, fv.y * rn, 0, false);
  ((unsigned short*)(fn + (size_t)row * D_SZ))[lane] = (unsigned short)(pk & 0xFFFF);

  int y = labels[row];
  float2 wv = ((const float2*)(w + (size_t)y * D_SZ))[lane];
  float d  = fv.x * wv.x + fv.y * wv.y;
  float ww = wv.x * wv.x + wv.y * wv.y;
  #pragma unroll
  for (int m = 1; m < 64; m <<= 1) {
    d  += __shfl_xor(d,  m, 64);
    ww += __shfl_xor(ww, m, 64);
  }
  if (lane == 0) {
    float c = d / (sqrtf(ff) * sqrtf(ww));
    c = fminf(1.0f, fmaxf(-1.0f, c));
    cosy[row] = c;
  }
}

// ---------------- fused MX-FP8 MFMA GEMM + softmax partials ----------------
// 4 independent waves/block; wave w owns rows r0+w*64..+63 and LDS slice
// lds[w*8192 .. +8192). Per wave: stage A (8 instrs) -> vmcnt(0) -> afrag ->
// stage B0,B1 -> loop {vmcnt(4); ds_read both j-frags; lgkm(0)+sched_barrier;
// prefetch B(sub+2) into the half just drained; MFMA/EPI pipelined}.
// NO s_barrier: each wave self-paced; buffers are wave-private.
// vmcnt ledger: steady state 8 outstanding (B(sub):4 oldest, B(sub+1):4);
// wait vmcnt(4) completes exactly B(sub); prefetch re-arms to 8.
__global__ __launch_bounds__(256, 4) void gemm_partial_kernel(
    const u8* __restrict__ fn, const u8* __restrict__ wn,
    float* __restrict__ ps) {
  __shared__ __align__(16) u8 lds[4 * 8192];  // 8KB per wave

  const int tid  = threadIdx.x;
  const int lane = tid & 63;
  const int wid  = tid >> 6;       // 0..3, independent waves
  const int cb   = blockIdx.y;     // 0..195
  const int r0   = blockIdx.x * BM;
  const int hi   = lane >> 4;
  const int l15  = lane & 15;

  u8* slice = &lds[(tid & ~63) * 128];         // == wid*8192, wave-uniform form

  // ---- stage own A (64 rows x 128B = 8KB) into the full slice ----
  const u8* abase = fn + (size_t)(r0 + wid * 64) * D_SZ;
  #pragma unroll
  for (int it = 0; it < 8; ++it) {
    int id = it * 64 + lane;                   // 16B chunk id (0..511)
    int r  = id >> 3;                          // 0..63
    int s  = (id & 7) ^ (r & 7);               // pre-swizzled source slot
    gload_lds16(abase + (size_t)r * D_SZ + s * 16, slice + it * 1024);
  }
  asm volatile("s_waitcnt vmcnt(0)" ::: "memory");

  // ---- A fragments -> registers (row_local = i*16+l15, K span hi*32..+32) ----
  i32x8 afrag[4];
  #pragma unroll
  for (int i = 0; i < 4; ++i) {
    int row = i * 16 + l15;
    int s0  = (hi * 2)     ^ (row & 7);
    int s1  = (hi * 2 + 1) ^ (row & 7);
    i32x4 lo = *(const i32x4*)&slice[row * D_SZ + s0 * 16];
    i32x4 h4 = *(const i32x4*)&slice[row * D_SZ + s1 * 16];
    afrag[i] = __builtin_shufflevector(lo, h4, 0, 1, 2, 3, 4, 5, 6, 7);
  }
  asm volatile("s_waitcnt lgkmcnt(0)" ::: "memory");
  __builtin_amdgcn_sched_barrier(0);           // rule #18: pin afrag reads

  // ---- B staging pointers ----
  const u8* bsrc[4];
  #pragma unroll
  for (int it = 0; it < 4; ++it) {
    int id = it * 64 + lane;                   // 16B chunk id (0..255)
    int cl = id >> 3;                          // 0..31
    int s  = (id & 7) ^ (cl & 7);
    bsrc[it] = wn + (size_t)(cb * CPB + cl) * D_SZ + s * 16;
  }
  // stage B(0) -> half0, B(1) -> half1
  #pragma unroll
  for (int it = 0; it < 4; ++it)
    gload_lds16(bsrc[it], slice + it * 1024);
  #pragma unroll
  for (int it = 0; it < 4; ++it)
    gload_lds16(bsrc[it] + BN * D_SZ, slice + 4096 + it * 1024);
  // R10 BUGFIX: one prefetch per iteration => advance ONE subtile per
  // iteration. Pre-advance to B(1); loop adds BN*D_SZ before each prefetch,
  // so iteration sub stages exactly B(sub+2).
  #pragma unroll
  for (int it = 0; it < 4; ++it)
    bsrc[it] += BN * D_SZ;

  // hoisted bfrag slot offsets: col = j*16 + l15
  int boff[2][2];
  #pragma unroll
  for (int j = 0; j < 2; ++j) {
    int col = j * 16 + l15;
    boff[j][0] = col * D_SZ + (((hi * 2)     ^ (col & 7)) * 16);
    boff[j][1] = col * D_SZ + (((hi * 2 + 1) ^ (col & 7)) * 16);
  }

  float sacc[4][4] = {};
  f32x4 acc0[4];
  f32x4 acc1[4] = {};            // zero-primed; consumed once (exact, POST_SUB)
  const f32x4 zero4 = {0.f, 0.f, 0.f, 0.f};

  #pragma unroll 1
  for (int sub = 0; sub < NSUB; ++sub) {
    if (sub < NSUB - 1) {
      asm volatile("s_waitcnt vmcnt(4)" ::: "memory");  // own B(sub) landed
    } else {
      asm volatile("s_waitcnt vmcnt(0)" ::: "memory");
    }
    u8* bhalf = slice + (sub & 1) * 4096;

    // read both j-phase fragments up front
    i32x8 b0, b1;
    {
      i32x4 lo0 = *(const i32x4*)&bhalf[boff[0][0]];
      i32x4 h40 = *(const i32x4*)&bhalf[boff[0][1]];
      i32x4 lo1 = *(const i32x4*)&bhalf[boff[1][0]];
      i32x4 h41 = *(const i32x4*)&bhalf[boff[1][1]];
      b0 = __builtin_shufflevector(lo0, h40, 0, 1, 2, 3, 4, 5, 6, 7);
      b1 = __builtin_shufflevector(lo1, h41, 0, 1, 2, 3, 4, 5, 6, 7);
    }
    asm volatile("s_waitcnt lgkmcnt(0)" ::: "memory");
    __builtin_amdgcn_sched_barrier(0);           // rule #18: MFMA must not hoist

    // prefetch B(sub+2) into this half (fully drained into regs above)
    if (sub < NSUB - 2) {
      #pragma unroll
      for (int it = 0; it < 4; ++it) {
        bsrc[it] += BN * D_SZ;                   // B(sub+1) -> B(sub+2)
        gload_lds16(bsrc[it], bhalf + it * 1024);
      }
    }

    // ---- j0: MFMA cluster, then epilogue of previous acc1 ----
    __builtin_amdgcn_s_setprio(1);
    #pragma unroll
    for (int i = 0; i < 4; ++i)
      acc0[i] = __builtin_amdgcn_mfma_scale_f32_16x16x128_f8f6f4(
          afrag[i], b0, zero4, 0, 0, 0, SCL_A, 0, SCL_B);
    __builtin_amdgcn_s_setprio(0);
    #pragma unroll
    for (int i = 0; i < 4; ++i) {
      f32x4 a4 = acc1[i];
      #pragma unroll
      for (int r = 0; r < 4; ++r)
        sacc[i][r] += __builtin_amdgcn_exp2f(a4[r]);
    }

    // ---- j1: MFMA cluster, then epilogue of acc0 ----
    __builtin_amdgcn_s_setprio(1);
    #pragma unroll
    for (int i = 0; i < 4; ++i)
      acc1[i] = __builtin_amdgcn_mfma_scale_f32_16x16x128_f8f6f4(
          afrag[i], b1, zero4, 0, 0, 0, SCL_A, 0, SCL_B);
    __builtin_amdgcn_s_setprio(0);
    #pragma unroll
    for (int i = 0; i < 4; ++i) {
      f32x4 a4 = acc0[i];
      #pragma unroll
      for (int r = 0; r < 4; ++r)
        sacc[i][r] += __builtin_amdgcn_exp2f(a4[r]);
    }
  }

  // ---- tail: epilogue of the last subtile's acc1 ----
  #pragma unroll
  for (int i = 0; i < 4; ++i) {
    f32x4 a4 = acc1[i];
    #pragma unroll
    for (int r = 0; r < 4; ++r)
      sacc[i][r] += __builtin_amdgcn_exp2f(a4[r]);
  }

  // ---- reduce across the 16 lanes sharing each row, write partials ----
  #pragma unroll
  for (int i = 0; i < 4; ++i)
    #pragma unroll
    for (int r = 0; r < 4; ++r) {
      float s = sacc[i][r];
      #pragma unroll
      for (int m = 1; m < 16; m <<= 1) s += __shfl_xor(s, m, 64);
      if (l15 == 0) {
        int rowg = r0 + wid * 64 + i * 16 + hi * 4 + r;
        ps[(size_t)rowg * NSLOT + cb] = s;
      }
    }
}

// ---------------- merge partials -> per-row loss ----------------
__global__ void merge_kernel(const float* __restrict__ ps,
                             const float* __restrict__ cosy,
                             float* __restrict__ losses) {
  int row  = (blockIdx.x * blockDim.x + threadIdx.x) >> 6;
  int lane = threadIdx.x & 63;
  if (row >= B_SZ) return;
  float s = 0.0f;
  for (int k = lane; k < NSLOT; k += 64) s += ps[(size_t)row * NSLOT + k];
  #pragma unroll
  for (int m = 1; m < 64; m <<= 1) s += __shfl_xor(s, m, 64);
  if (lane == 0) {
    float cy  = cosy[row];
    float zy2 = C2LOG * cy;                 // log2-domain label logit
    s = s - POST_SUB - exp2f(zy2) + exp2f(zy2 - M2LOG);
    s = fmaxf(s, 1e-30f);
    float lse = logf(s);
    losses[row] = lse - 0.9f * (S_SC * cy - 9.0f);
  }
}

// ---------------- deterministic mean over B ----------------
__global__ void final_kernel(const float* __restrict__ losses, float* __restrict__ out) {
  __shared__ float red[256];
  int tid = threadIdx.x;
  float s = 0.0f;
  for (int k = tid; k < B_SZ; k += 256) s += losses[k];
  red[tid] = s;
  __syncthreads();
  for (int off = 128; off > 0; off >>= 1) {
    if (tid < off) red[tid] += red[tid + off];
    __syncthreads();
  }
  if (tid == 0) out[0] = red[0] / (float)B_SZ;
}

extern "C" void kernel_launch(void* const* d_in, const int* in_sizes, int n_in,
                              void* d_out, int out_size, void* d_ws, size_t ws_size,
                              hipStream_t stream) {
  const float* feat   = (const float*)d_in[0];
  const int*   labels = (const int*)d_in[1];
  const float* weight = (const float*)d_in[2];
  float* out = (float*)d_out;

  char* ws = (char*)d_ws;
  size_t off = 0;
  u8* wn = (u8*)(ws + off);          off += (size_t)C_PAD * D_SZ;      // 12.85 MB
  off = (off + 255) & ~(size_t)255;
  u8* fn = (u8*)(ws + off);          off += (size_t)B_SZ * D_SZ;       // 256 KB
  off = (off + 255) & ~(size_t)255;
  float* cosy = (float*)(ws + off);  off += (size_t)B_SZ * 4;
  off = (off + 255) & ~(size_t)255;
  float* ps = (float*)(ws + off);    off += (size_t)B_SZ * NSLOT * 4;  // 1.6 MB
  off = (off + 255) & ~(size_t)255;
  float* losses = (float*)(ws + off);

  rownorm_fp8_kernel<<<(C_PAD + 3) / 4, 256, 0, stream>>>(weight, wn, C_PAD, C_SZ, B_QS);
  prep_f_kernel<<<(B_SZ + 3) / 4, 256, 0, stream>>>(feat, labels, weight, fn, cosy);

  dim3 grid(B_SZ / BM, GRID_C);   // x = row tiles (8), y = col chunks (196)
  gemm_partial_kernel<<<grid, 256, 0, stream>>>(fn, wn, ps);

  merge_kernel<<<(B_SZ + 3) / 4, 256, 0, stream>>>(ps, cosy, losses);
  final_kernel<<<1, 256, 0, stream>>>(losses, out);
}